// Round 1
// baseline (569.088 us; speedup 1.0000x reference)
//
#include <hip/hip_runtime.h>
#include <stdint.h>

// Problem constants
#define TB   2048           // sequence length T
#define NB   4              // batch B
#define DIM  1024           // model dim D
#define NH   16             // heads
#define HD   64             // head dim
#define ROWS (NB * TB)      // 8192 flattened tokens

typedef __attribute__((ext_vector_type(8))) short s16x8;   // 8 bf16 (4 VGPRs) MFMA A/B frag
typedef __attribute__((ext_vector_type(4))) short s16x4;
typedef __attribute__((ext_vector_type(4))) float f32x4;   // MFMA C/D frag

// ---------- bf16 helpers (bit-level, RNE) ----------
__device__ __forceinline__ unsigned short f2bf(float f) {
  union { float f; unsigned u; } v; v.f = f;
  unsigned r = v.u + 0x7FFFu + ((v.u >> 16) & 1u);
  return (unsigned short)(r >> 16);
}

// ---------- async global->LDS 16B (wave-uniform LDS base + lane*16) ----------
__device__ __forceinline__ void load_lds16(const void* g, void* l) {
  __builtin_amdgcn_global_load_lds(
      (const __attribute__((address_space(1))) void*)g,
      (__attribute__((address_space(3))) void*)l, 16, 0, 0);
}

// ============================================================
// Prep: x (fp32) -> bf16, row-major [8192][1024]
// ============================================================
__global__ __launch_bounds__(256) void conv_x(const float* __restrict__ x,
                                              short* __restrict__ x1) {
  const int i = blockIdx.x * 256 + threadIdx.x;       // handles 4 floats
  const float4 v = ((const float4*)x)[i];
  s16x4 o;
  o[0] = (short)f2bf(v.x); o[1] = (short)f2bf(v.y);
  o[2] = (short)f2bf(v.z); o[3] = (short)f2bf(v.w);
  *(s16x4*)&x1[(size_t)i * 4] = o;
}

// ============================================================
// Prep: weights fp32 [k][n] -> bf16 transposed [n][k]
// ============================================================
__global__ __launch_bounds__(256) void prep_weights(
    const float* __restrict__ wq, const float* __restrict__ wk,
    const float* __restrict__ wv, const float* __restrict__ wo,
    short* __restrict__ wqT, short* __restrict__ wkT,
    short* __restrict__ wvT, short* __restrict__ woT) {
  __shared__ float tile[32][33];
  const float* src = (blockIdx.z == 0) ? wq : (blockIdx.z == 1) ? wk
                   : (blockIdx.z == 2) ? wv : wo;
  short* dst = (blockIdx.z == 0) ? wqT : (blockIdx.z == 1) ? wkT
             : (blockIdx.z == 2) ? wvT : woT;
  const int k0 = blockIdx.x * 32, n0 = blockIdx.y * 32;
  const int tx = threadIdx.x & 31, ty = threadIdx.x >> 5;  // ty in [0,8)
  #pragma unroll
  for (int j = 0; j < 32; j += 8)
    tile[ty + j][tx] = src[(size_t)(k0 + ty + j) * DIM + n0 + tx];
  __syncthreads();
  #pragma unroll
  for (int j = 0; j < 32; j += 8)
    dst[(size_t)(n0 + ty + j) * DIM + k0 + tx] = (short)f2bf(tile[tx][ty + j]);
}

// ============================================================
// GEMM core: C[128x128] += A[128xK] * Bt[128xK]^T, BK=32,
// 4 waves, 4x4 16x16x32 frags per wave, global_load_lds staging.
// A: [rows][lda] bf16 row-major; Bt: [ncols][1024] bf16 (B transposed).
// ============================================================
__device__ __forceinline__ void gemm_core(
    const short* __restrict__ A, int lda, const short* __restrict__ Bt,
    int kiters, int row0, int colw, short* As, short* Bs, f32x4 acc[4][4]) {
  const int tid  = threadIdx.x;
  const int lane = tid & 63;
  const int w    = tid >> 6;
  const int g = lane >> 4, li = lane & 15;
  const int wrow = (w >> 1) << 6, wcol = (w & 1) << 6;
  // staging map: call j covers LDS elems (w*2+j)*512 + lane*8 -> (m,k)
  const int sr0 = w * 32 + (lane >> 2);   // m for j=0
  const int sr1 = sr0 + 16;               // m for j=1
  const int sk  = (lane & 3) << 3;        // k base (8 bf16 = 16B)
  const f32x4 fzero = {0.f, 0.f, 0.f, 0.f};
  #pragma unroll
  for (int mi = 0; mi < 4; ++mi)
    #pragma unroll
    for (int ni = 0; ni < 4; ++ni) acc[mi][ni] = fzero;

  for (int it = 0; it < kiters; ++it) {
    const int kb = it << 5;
    load_lds16(A  + (size_t)(row0 + sr0) * lda + kb + sk, &As[(w * 2 + 0) * 512]);
    load_lds16(A  + (size_t)(row0 + sr1) * lda + kb + sk, &As[(w * 2 + 1) * 512]);
    load_lds16(Bt + (size_t)(colw + sr0) * DIM + kb + sk, &Bs[(w * 2 + 0) * 512]);
    load_lds16(Bt + (size_t)(colw + sr1) * DIM + kb + sk, &Bs[(w * 2 + 1) * 512]);
    __syncthreads();   // vmcnt(0) drain + barrier
    s16x8 af[4], bfr[4];
    #pragma unroll
    for (int mi = 0; mi < 4; ++mi)
      af[mi] = *(const s16x8*)&As[(wrow + mi * 16 + li) * 32 + g * 8];
    #pragma unroll
    for (int ni = 0; ni < 4; ++ni)
      bfr[ni] = *(const s16x8*)&Bs[(wcol + ni * 16 + li) * 32 + g * 8];
    #pragma unroll
    for (int mi = 0; mi < 4; ++mi)
      #pragma unroll
      for (int ni = 0; ni < 4; ++ni)
        acc[mi][ni] = __builtin_amdgcn_mfma_f32_16x16x32_bf16(
            af[mi], bfr[ni], acc[mi][ni], 0, 0, 0);
    __syncthreads();   // protect LDS before next stage
  }
}

// ============================================================
// Fused QKV projection. Grid (64, 24): x=M/128, y=3072/128.
// Writes Q (pre-scaled by 0.125*log2e) and K as [B,H,T,HD] bf16,
// V transposed as [B,H,HD,T] bf16.
// ============================================================
__global__ __launch_bounds__(256) void gemm_qkv(
    const short* __restrict__ x1,
    const short* __restrict__ wqT, const short* __restrict__ wkT,
    const short* __restrict__ wvT,
    short* __restrict__ Q, short* __restrict__ Kc, short* __restrict__ Vt) {
  __shared__ __attribute__((aligned(16))) short As[4096];
  __shared__ __attribute__((aligned(16))) short Bs[4096];
  const int row0 = blockIdx.x << 7;
  const int col0 = blockIdx.y << 7;
  const int wsel = col0 >> 10;          // 0=Q 1=K 2=V (128-col tile never crosses)
  const int colw = col0 & 1023;
  const short* Bt = (wsel == 0) ? wqT : (wsel == 1) ? wkT : wvT;
  f32x4 acc[4][4];
  gemm_core(x1, DIM, Bt, DIM / 32, row0, colw, As, Bs, acc);

  const int lane = threadIdx.x & 63, w = threadIdx.x >> 6;
  const int g = lane >> 4, li = lane & 15;
  const int wrow = (w >> 1) << 6, wcol = (w & 1) << 6;
  const float qscale = 0.125f * 1.44269504088896340736f;  // softmax scale * log2(e)
  #pragma unroll
  for (int mi = 0; mi < 4; ++mi) {
    #pragma unroll
    for (int r = 0; r < 4; ++r) {
      const int row = row0 + wrow + mi * 16 + g * 4 + r;
      const int b = row >> 11, t = row & (TB - 1);
      #pragma unroll
      for (int ni = 0; ni < 4; ++ni) {
        const int nc = colw + wcol + ni * 16 + li;
        const int h = nc >> 6, d = nc & 63;
        const int bh = b * NH + h;
        const float v = acc[mi][ni][r];
        if (wsel == 0)
          Q[((size_t)bh * TB + t) * HD + d] = (short)f2bf(v * qscale);
        else if (wsel == 1)
          Kc[((size_t)bh * TB + t) * HD + d] = (short)f2bf(v);
        else
          Vt[((size_t)bh * HD + d) * TB + t] = (short)f2bf(v);
      }
    }
  }
}

// ============================================================
// Flash attention (NO mask). Grid (32, 64): x=T/64 q-tiles, y=B*H.
// 4 waves/block, 16 q-rows/wave, KV tile = 32.
// Q pre-scaled so S is log2-domain logits; softmax uses exp2.
// ============================================================
__global__ __launch_bounds__(256) void attn(
    const short* __restrict__ Q, const short* __restrict__ Kc,
    const short* __restrict__ Vt, short* __restrict__ ctx) {
  __shared__ __attribute__((aligned(16))) short Plds[4][16 * 40];  // stride 40: bank-friendly
  const int tid = threadIdx.x, lane = tid & 63, w = tid >> 6;
  const int g = lane >> 4, li = lane & 15;
  const int bh = blockIdx.y;
  const int q0 = (blockIdx.x << 6) + (w << 4);
  const short* Qh = Q  + (size_t)bh * TB * HD;
  const short* Kh = Kc + (size_t)bh * TB * HD;
  const short* Vh = Vt + (size_t)bh * HD * TB;
  short* Pw = (short*)Plds[w];

  // Q A-frags for this wave's 16 rows (row=li, k=g*8+i), d-chunks 0/1
  const s16x8 aq0 = *(const s16x8*)&Qh[(size_t)(q0 + li) * HD + g * 8];
  const s16x8 aq1 = *(const s16x8*)&Qh[(size_t)(q0 + li) * HD + 32 + g * 8];

  f32x4 O[4];
  float mrun[4], srun[4];
  const f32x4 fzero = {0.f, 0.f, 0.f, 0.f};
  #pragma unroll
  for (int n = 0; n < 4; ++n) O[n] = fzero;
  #pragma unroll
  for (int r = 0; r < 4; ++r) { mrun[r] = -1e30f; srun[r] = 0.f; }

  for (int tk = 0; tk < TB; tk += 32) {
    f32x4 S0 = fzero, S1 = fzero;
    {
      s16x8 bk;
      bk = *(const s16x8*)&Kh[(size_t)(tk + li) * HD + g * 8];
      S0 = __builtin_amdgcn_mfma_f32_16x16x32_bf16(aq0, bk, S0, 0, 0, 0);
      bk = *(const s16x8*)&Kh[(size_t)(tk + li) * HD + 32 + g * 8];
      S0 = __builtin_amdgcn_mfma_f32_16x16x32_bf16(aq1, bk, S0, 0, 0, 0);
      bk = *(const s16x8*)&Kh[(size_t)(tk + 16 + li) * HD + g * 8];
      S1 = __builtin_amdgcn_mfma_f32_16x16x32_bf16(aq0, bk, S1, 0, 0, 0);
      bk = *(const s16x8*)&Kh[(size_t)(tk + 16 + li) * HD + 32 + g * 8];
      S1 = __builtin_amdgcn_mfma_f32_16x16x32_bf16(aq1, bk, S1, 0, 0, 0);
    }
    // online softmax: full max-reduce per row (required), sum kept per-lane partial
    #pragma unroll
    for (int r = 0; r < 4; ++r) {
      float mx = fmaxf(S0[r], S1[r]);
      mx = fmaxf(mx, __shfl_xor(mx, 1));
      mx = fmaxf(mx, __shfl_xor(mx, 2));
      mx = fmaxf(mx, __shfl_xor(mx, 4));
      mx = fmaxf(mx, __shfl_xor(mx, 8));
      const float mnew = fmaxf(mrun[r], mx);
      const float cf = __builtin_amdgcn_exp2f(mrun[r] - mnew);
      mrun[r] = mnew;
      const float e0 = __builtin_amdgcn_exp2f(S0[r] - mnew);
      const float e1 = __builtin_amdgcn_exp2f(S1[r] - mnew);
      srun[r] = srun[r] * cf + (e0 + e1);
      O[0][r] *= cf; O[1][r] *= cf; O[2][r] *= cf; O[3][r] *= cf;
      const int prow = g * 4 + r;                 // D-layout row
      Pw[prow * 40 + li]      = (short)f2bf(e0);
      Pw[prow * 40 + 16 + li] = (short)f2bf(e1);
    }
    __syncthreads();
    const s16x8 pa = *(const s16x8*)&Pw[li * 40 + g * 8];  // A-frag: row=li, k=g*8+i
    #pragma unroll
    for (int n = 0; n < 4; ++n) {
      const s16x8 bv = *(const s16x8*)&Vh[(size_t)(n * 16 + li) * TB + tk + g * 8];
      O[n] = __builtin_amdgcn_mfma_f32_16x16x32_bf16(pa, bv, O[n], 0, 0, 0);
    }
    __syncthreads();
  }
  // deferred sum reduce + normalize + store ctx [B,T,H*HD] bf16
  #pragma unroll
  for (int r = 0; r < 4; ++r) {
    srun[r] += __shfl_xor(srun[r], 1);
    srun[r] += __shfl_xor(srun[r], 2);
    srun[r] += __shfl_xor(srun[r], 4);
    srun[r] += __shfl_xor(srun[r], 8);
  }
  const int b = bh >> 4, h = bh & 15;
  #pragma unroll
  for (int r = 0; r < 4; ++r) {
    const int t = q0 + g * 4 + r;
    const float inv = 1.f / srun[r];
    #pragma unroll
    for (int n = 0; n < 4; ++n)
      ctx[((size_t)(b * TB + t)) * DIM + h * HD + n * 16 + li] =
          (short)f2bf(O[n][r] * inv);
  }
}

// ============================================================
// Output projection + bias, fp32 out. Grid (64, 8).
// ============================================================
__global__ __launch_bounds__(256) void gemm_out(
    const short* __restrict__ ctx, const short* __restrict__ woT,
    const float* __restrict__ bo, float* __restrict__ out) {
  __shared__ __attribute__((aligned(16))) short As[4096];
  __shared__ __attribute__((aligned(16))) short Bs[4096];
  const int row0 = blockIdx.x << 7;
  const int col0 = blockIdx.y << 7;
  f32x4 acc[4][4];
  gemm_core(ctx, DIM, woT, DIM / 32, row0, col0, As, Bs, acc);
  const int lane = threadIdx.x & 63, w = threadIdx.x >> 6;
  const int g = lane >> 4, li = lane & 15;
  const int wrow = (w >> 1) << 6, wcol = (w & 1) << 6;
  #pragma unroll
  for (int mi = 0; mi < 4; ++mi)
    #pragma unroll
    for (int r = 0; r < 4; ++r) {
      const int row = row0 + wrow + mi * 16 + g * 4 + r;
      #pragma unroll
      for (int ni = 0; ni < 4; ++ni) {
        const int nc = col0 + wcol + ni * 16 + li;
        out[(size_t)row * DIM + nc] = acc[mi][ni][r] + bo[nc];
      }
    }
}

// ============================================================
extern "C" void kernel_launch(void* const* d_in, const int* in_sizes, int n_in,
                              void* d_out, int out_size, void* d_ws, size_t ws_size,
                              hipStream_t stream) {
  const float* x   = (const float*)d_in[0];
  const float* w_q = (const float*)d_in[1];
  const float* w_k = (const float*)d_in[2];
  const float* w_v = (const float*)d_in[3];
  const float* w_o = (const float*)d_in[4];
  const float* b_o = (const float*)d_in[5];
  float* out = (float*)d_out;

  // Workspace layout (~75.5 MB total)
  char* p = (char*)d_ws;
  short* x1  = (short*)p; p += (size_t)ROWS * DIM * 2;   // 16.8 MB
  short* wqT = (short*)p; p += (size_t)DIM * DIM * 2;    // 2 MB each
  short* wkT = (short*)p; p += (size_t)DIM * DIM * 2;
  short* wvT = (short*)p; p += (size_t)DIM * DIM * 2;
  short* woT = (short*)p; p += (size_t)DIM * DIM * 2;
  short* Qb  = (short*)p; p += (size_t)ROWS * DIM * 2;   // 16.8 MB each
  short* Kb  = (short*)p; p += (size_t)ROWS * DIM * 2;
  short* Vtb = (short*)p; p += (size_t)ROWS * DIM * 2;
  short* ctx = x1;  // x1 is dead after gemm_qkv; reuse for context

  conv_x<<<ROWS * DIM / 4 / 256, 256, 0, stream>>>(x, x1);
  prep_weights<<<dim3(32, 32, 4), 256, 0, stream>>>(w_q, w_k, w_v, w_o,
                                                    wqT, wkT, wvT, woT);
  gemm_qkv<<<dim3(ROWS / 128, 3 * DIM / 128), 256, 0, stream>>>(
      x1, wqT, wkT, wvT, Qb, Kb, Vtb);
  attn<<<dim3(TB / 64, NB * NH), 256, 0, stream>>>(Qb, Kb, Vtb, ctx);
  gemm_out<<<dim3(ROWS / 128, DIM / 128), 256, 0, stream>>>(ctx, woT, b_o, out);
}

// Round 2
// 404.573 us; speedup vs baseline: 1.4066x; 1.4066x over previous
//
#include <hip/hip_runtime.h>
#include <stdint.h>

// Problem constants
#define TB   2048           // sequence length T
#define NB   4              // batch B
#define DIM  1024           // model dim D
#define NH   16             // heads
#define HD   64             // head dim
#define ROWS (NB * TB)      // 8192 flattened tokens

typedef __attribute__((ext_vector_type(8)))  short s16x8;   // 8 bf16 (4 VGPRs) MFMA A/B frag
typedef __attribute__((ext_vector_type(4)))  short s16x4;
typedef __attribute__((ext_vector_type(4)))  float f32x4;   // 16x16 MFMA C/D frag
typedef __attribute__((ext_vector_type(16))) float f32x16;  // 32x32 MFMA C/D frag

// ---------- bf16 helpers (bit-level, RNE) ----------
__device__ __forceinline__ unsigned short f2bf(float f) {
  union { float f; unsigned u; } v; v.f = f;
  unsigned r = v.u + 0x7FFFu + ((v.u >> 16) & 1u);
  return (unsigned short)(r >> 16);
}

// ---------- async global->LDS 16B (wave-uniform LDS base + lane*16) ----------
__device__ __forceinline__ void load_lds16(const void* g, void* l) {
  __builtin_amdgcn_global_load_lds(
      (const __attribute__((address_space(1))) void*)g,
      (__attribute__((address_space(3))) void*)l, 16, 0, 0);
}

// ============================================================
// Prep: x (fp32) -> bf16, row-major [8192][1024]
// ============================================================
__global__ __launch_bounds__(256) void conv_x(const float* __restrict__ x,
                                              short* __restrict__ x1) {
  const int i = blockIdx.x * 256 + threadIdx.x;       // handles 4 floats
  const float4 v = ((const float4*)x)[i];
  s16x4 o;
  o[0] = (short)f2bf(v.x); o[1] = (short)f2bf(v.y);
  o[2] = (short)f2bf(v.z); o[3] = (short)f2bf(v.w);
  *(s16x4*)&x1[(size_t)i * 4] = o;
}

// ============================================================
// Prep: weights fp32 [k][n] -> bf16 transposed [n][k]
// ============================================================
__global__ __launch_bounds__(256) void prep_weights(
    const float* __restrict__ wq, const float* __restrict__ wk,
    const float* __restrict__ wv, const float* __restrict__ wo,
    short* __restrict__ wqT, short* __restrict__ wkT,
    short* __restrict__ wvT, short* __restrict__ woT) {
  __shared__ float tile[32][33];
  const float* src = (blockIdx.z == 0) ? wq : (blockIdx.z == 1) ? wk
                   : (blockIdx.z == 2) ? wv : wo;
  short* dst = (blockIdx.z == 0) ? wqT : (blockIdx.z == 1) ? wkT
             : (blockIdx.z == 2) ? wvT : woT;
  const int k0 = blockIdx.x * 32, n0 = blockIdx.y * 32;
  const int tx = threadIdx.x & 31, ty = threadIdx.x >> 5;  // ty in [0,8)
  #pragma unroll
  for (int j = 0; j < 32; j += 8)
    tile[ty + j][tx] = src[(size_t)(k0 + ty + j) * DIM + n0 + tx];
  __syncthreads();
  #pragma unroll
  for (int j = 0; j < 32; j += 8)
    dst[(size_t)(n0 + ty + j) * DIM + k0 + tx] = (short)f2bf(tile[tx][ty + j]);
}

// ============================================================
// GEMM core: C[128x128] += A[128xK] * Bt[128xK]^T, BK=32,
// 4 waves, 4x4 16x16x32 frags per wave, global_load_lds staging.
// ============================================================
__device__ __forceinline__ void gemm_core(
    const short* __restrict__ A, int lda, const short* __restrict__ Bt,
    int kiters, int row0, int colw, short* As, short* Bs, f32x4 acc[4][4]) {
  const int tid  = threadIdx.x;
  const int lane = tid & 63;
  const int w    = tid >> 6;
  const int g = lane >> 4, li = lane & 15;
  const int wrow = (w >> 1) << 6, wcol = (w & 1) << 6;
  const int sr0 = w * 32 + (lane >> 2);   // m for j=0
  const int sr1 = sr0 + 16;               // m for j=1
  const int sk  = (lane & 3) << 3;        // k base (8 bf16 = 16B)
  const f32x4 fzero = {0.f, 0.f, 0.f, 0.f};
  #pragma unroll
  for (int mi = 0; mi < 4; ++mi)
    #pragma unroll
    for (int ni = 0; ni < 4; ++ni) acc[mi][ni] = fzero;

  for (int it = 0; it < kiters; ++it) {
    const int kb = it << 5;
    load_lds16(A  + (size_t)(row0 + sr0) * lda + kb + sk, &As[(w * 2 + 0) * 512]);
    load_lds16(A  + (size_t)(row0 + sr1) * lda + kb + sk, &As[(w * 2 + 1) * 512]);
    load_lds16(Bt + (size_t)(colw + sr0) * DIM + kb + sk, &Bs[(w * 2 + 0) * 512]);
    load_lds16(Bt + (size_t)(colw + sr1) * DIM + kb + sk, &Bs[(w * 2 + 1) * 512]);
    __syncthreads();
    s16x8 af[4], bfr[4];
    #pragma unroll
    for (int mi = 0; mi < 4; ++mi)
      af[mi] = *(const s16x8*)&As[(wrow + mi * 16 + li) * 32 + g * 8];
    #pragma unroll
    for (int ni = 0; ni < 4; ++ni)
      bfr[ni] = *(const s16x8*)&Bs[(wcol + ni * 16 + li) * 32 + g * 8];
    #pragma unroll
    for (int mi = 0; mi < 4; ++mi)
      #pragma unroll
      for (int ni = 0; ni < 4; ++ni)
        acc[mi][ni] = __builtin_amdgcn_mfma_f32_16x16x32_bf16(
            af[mi], bfr[ni], acc[mi][ni], 0, 0, 0);
    __syncthreads();
  }
}

// ============================================================
// Fused QKV projection. Grid (64, 24).
// Q pre-scaled by 0.125*log2e; K as [B,H,T,HD]; V^T as [B,H,HD,T].
// ============================================================
__global__ __launch_bounds__(256) void gemm_qkv(
    const short* __restrict__ x1,
    const short* __restrict__ wqT, const short* __restrict__ wkT,
    const short* __restrict__ wvT,
    short* __restrict__ Q, short* __restrict__ Kc, short* __restrict__ Vt) {
  __shared__ __attribute__((aligned(16))) short As[4096];
  __shared__ __attribute__((aligned(16))) short Bs[4096];
  const int row0 = blockIdx.x << 7;
  const int col0 = blockIdx.y << 7;
  const int wsel = col0 >> 10;
  const int colw = col0 & 1023;
  const short* Bt = (wsel == 0) ? wqT : (wsel == 1) ? wkT : wvT;
  f32x4 acc[4][4];
  gemm_core(x1, DIM, Bt, DIM / 32, row0, colw, As, Bs, acc);

  const int lane = threadIdx.x & 63, w = threadIdx.x >> 6;
  const int g = lane >> 4, li = lane & 15;
  const int wrow = (w >> 1) << 6, wcol = (w & 1) << 6;
  const float qscale = 0.125f * 1.44269504088896340736f;  // 1/sqrt(64) * log2(e)
  #pragma unroll
  for (int mi = 0; mi < 4; ++mi) {
    #pragma unroll
    for (int r = 0; r < 4; ++r) {
      const int row = row0 + wrow + mi * 16 + g * 4 + r;
      const int b = row >> 11, t = row & (TB - 1);
      #pragma unroll
      for (int ni = 0; ni < 4; ++ni) {
        const int nc = colw + wcol + ni * 16 + li;
        const int h = nc >> 6, d = nc & 63;
        const int bh = b * NH + h;
        const float v = acc[mi][ni][r];
        if (wsel == 0)
          Q[((size_t)bh * TB + t) * HD + d] = (short)f2bf(v * qscale);
        else if (wsel == 1)
          Kc[((size_t)bh * TB + t) * HD + d] = (short)f2bf(v);
        else
          Vt[((size_t)bh * HD + d) * TB + t] = (short)f2bf(v);
      }
    }
  }
}

// ============================================================
// Flash attention (NO mask), swapped-operand 32x32 structure.
// Grid (16, 64): x = T/128 (4 waves x 32 q-rows), y = B*H.
// Zero LDS, zero __syncthreads — waves fully independent.
// Per KV tile of 32:
//   S^T = mfma32x32x16(K, Q) x4   -> lane owns q=lane&31, 16 kv rows
//   in-register softmax (1 shfl_xor(32) for the max)
//   P packed to bf16 dwords, partner-exchanged via shfl_xor(32)
//   O^T += mfma32x32x16(V^T, P^T) x4  (lane ownership matches softmax)
// Q was pre-scaled by 0.125*log2e so exp2 is the correct softmax exp.
// ============================================================
__global__ __launch_bounds__(256) void attn(
    const short* __restrict__ Q, const short* __restrict__ Kc,
    const short* __restrict__ Vt, short* __restrict__ ctx) {
  const int tid = threadIdx.x, lane = tid & 63, w = tid >> 6;
  const int li = lane & 31, hi = lane >> 5;
  const int bh = blockIdx.y;
  const int q0 = (blockIdx.x << 7) + (w << 5);
  const short* Qh = Q  + (size_t)bh * TB * HD;
  const short* Kh = Kc + (size_t)bh * TB * HD;
  const short* Vh = Vt + (size_t)bh * HD * TB;

  // Q B-frags: col q = q0+li, k(d) = db*16 + hi*8 + j
  s16x8 qf[4];
  #pragma unroll
  for (int db = 0; db < 4; ++db)
    qf[db] = *(const s16x8*)&Qh[(size_t)(q0 + li) * HD + db * 16 + hi * 8];

  f32x16 O0, O1;
  #pragma unroll
  for (int i = 0; i < 16; ++i) { O0[i] = 0.f; O1[i] = 0.f; }
  float mrun = -1e30f, srun = 0.f;

  for (int kv0 = 0; kv0 < TB; kv0 += 32) {
    // ---- S^T[kv][q] ----
    f32x16 s;
    #pragma unroll
    for (int i = 0; i < 16; ++i) s[i] = 0.f;
    #pragma unroll
    for (int db = 0; db < 4; ++db) {
      const s16x8 kf =
          *(const s16x8*)&Kh[(size_t)(kv0 + li) * HD + db * 16 + hi * 8];
      s = __builtin_amdgcn_mfma_f32_32x32x16_bf16(kf, qf[db], s, 0, 0, 0);
    }
    // ---- online softmax (log2 domain), lane owns one q ----
    float t0 = fmaxf(fmaxf(s[0], s[1]), fmaxf(s[2], s[3]));
    float t1 = fmaxf(fmaxf(s[4], s[5]), fmaxf(s[6], s[7]));
    float t2 = fmaxf(fmaxf(s[8], s[9]), fmaxf(s[10], s[11]));
    float t3 = fmaxf(fmaxf(s[12], s[13]), fmaxf(s[14], s[15]));
    float pmax = fmaxf(fmaxf(t0, t1), fmaxf(t2, t3));
    pmax = fmaxf(pmax, __shfl_xor(pmax, 32));
    const float mnew = fmaxf(mrun, pmax);
    const float cf = __builtin_amdgcn_exp2f(mrun - mnew);
    mrun = mnew;
    float p[16];
    #pragma unroll
    for (int i = 0; i < 16; ++i) p[i] = __builtin_amdgcn_exp2f(s[i] - mnew);
    float ps0 = 0.f, ps1 = 0.f, ps2 = 0.f, ps3 = 0.f;
    #pragma unroll
    for (int i = 0; i < 4; ++i) {
      ps0 += p[i]; ps1 += p[4 + i]; ps2 += p[8 + i]; ps3 += p[12 + i];
    }
    srun = srun * cf + ((ps0 + ps1) + (ps2 + ps3));
    #pragma unroll
    for (int i = 0; i < 16; ++i) { O0[i] *= cf; O1[i] *= cf; }
    // ---- pack P -> bf16 dwords; partner exchange; build B-frags ----
    // own rows: c[i] = rows (pair) per C/D layout r = (reg&3)+8*(reg>>2)+4*hi
    unsigned c[8];
    #pragma unroll
    for (int i = 0; i < 8; ++i)
      c[i] = (unsigned)f2bf(p[2 * i]) | ((unsigned)f2bf(p[2 * i + 1]) << 16);
    unsigned rc[8];
    #pragma unroll
    for (int i = 0; i < 8; ++i)
      rc[i] = (unsigned)__shfl_xor((int)c[i], 32);
    union { s16x8 v; unsigned u[4]; } pb0, pb1;
    pb0.u[0] = hi ? rc[2] : c[0];
    pb0.u[1] = hi ? rc[3] : c[1];
    pb0.u[2] = hi ? c[2] : rc[0];
    pb0.u[3] = hi ? c[3] : rc[1];
    pb1.u[0] = hi ? rc[6] : c[4];
    pb1.u[1] = hi ? rc[7] : c[5];
    pb1.u[2] = hi ? c[6] : rc[4];
    pb1.u[3] = hi ? c[7] : rc[5];
    // ---- O^T += V^T * P^T ----
    {
      const s16x8 v00 = *(const s16x8*)&Vh[(size_t)li * TB + kv0 + hi * 8];
      O0 = __builtin_amdgcn_mfma_f32_32x32x16_bf16(v00, pb0.v, O0, 0, 0, 0);
      const s16x8 v01 = *(const s16x8*)&Vh[(size_t)li * TB + kv0 + 16 + hi * 8];
      O0 = __builtin_amdgcn_mfma_f32_32x32x16_bf16(v01, pb1.v, O0, 0, 0, 0);
      const s16x8 v10 = *(const s16x8*)&Vh[(size_t)(32 + li) * TB + kv0 + hi * 8];
      O1 = __builtin_amdgcn_mfma_f32_32x32x16_bf16(v10, pb0.v, O1, 0, 0, 0);
      const s16x8 v11 =
          *(const s16x8*)&Vh[(size_t)(32 + li) * TB + kv0 + 16 + hi * 8];
      O1 = __builtin_amdgcn_mfma_f32_32x32x16_bf16(v11, pb1.v, O1, 0, 0, 0);
    }
  }

  // ---- normalize + store ctx [B,T,H*HD] bf16 ----
  srun += __shfl_xor(srun, 32);
  const float inv = 1.f / srun;
  const int b = bh >> 4, h = bh & 15;
  const int q = q0 + li;
  short* outp = &ctx[((size_t)(b * TB + q)) * DIM + h * HD];
  #pragma unroll
  for (int u = 0; u < 4; ++u) {
    s16x4 o;
    #pragma unroll
    for (int v = 0; v < 4; ++v) o[v] = (short)f2bf(O0[u * 4 + v] * inv);
    *(s16x4*)&outp[8 * u + 4 * hi] = o;        // d = 8u + 4hi + v
    #pragma unroll
    for (int v = 0; v < 4; ++v) o[v] = (short)f2bf(O1[u * 4 + v] * inv);
    *(s16x4*)&outp[32 + 8 * u + 4 * hi] = o;   // d = 32 + 8u + 4hi + v
  }
}

// ============================================================
// Output projection + bias, fp32 out. Grid (64, 8).
// ============================================================
__global__ __launch_bounds__(256) void gemm_out(
    const short* __restrict__ ctx, const short* __restrict__ woT,
    const float* __restrict__ bo, float* __restrict__ out) {
  __shared__ __attribute__((aligned(16))) short As[4096];
  __shared__ __attribute__((aligned(16))) short Bs[4096];
  const int row0 = blockIdx.x << 7;
  const int col0 = blockIdx.y << 7;
  f32x4 acc[4][4];
  gemm_core(ctx, DIM, woT, DIM / 32, row0, col0, As, Bs, acc);
  const int lane = threadIdx.x & 63, w = threadIdx.x >> 6;
  const int g = lane >> 4, li = lane & 15;
  const int wrow = (w >> 1) << 6, wcol = (w & 1) << 6;
  #pragma unroll
  for (int mi = 0; mi < 4; ++mi)
    #pragma unroll
    for (int r = 0; r < 4; ++r) {
      const int row = row0 + wrow + mi * 16 + g * 4 + r;
      #pragma unroll
      for (int ni = 0; ni < 4; ++ni) {
        const int nc = col0 + wcol + ni * 16 + li;
        out[(size_t)row * DIM + nc] = acc[mi][ni][r] + bo[nc];
      }
    }
}

// ============================================================
extern "C" void kernel_launch(void* const* d_in, const int* in_sizes, int n_in,
                              void* d_out, int out_size, void* d_ws, size_t ws_size,
                              hipStream_t stream) {
  const float* x   = (const float*)d_in[0];
  const float* w_q = (const float*)d_in[1];
  const float* w_k = (const float*)d_in[2];
  const float* w_v = (const float*)d_in[3];
  const float* w_o = (const float*)d_in[4];
  const float* b_o = (const float*)d_in[5];
  float* out = (float*)d_out;

  char* p = (char*)d_ws;
  short* x1  = (short*)p; p += (size_t)ROWS * DIM * 2;
  short* wqT = (short*)p; p += (size_t)DIM * DIM * 2;
  short* wkT = (short*)p; p += (size_t)DIM * DIM * 2;
  short* wvT = (short*)p; p += (size_t)DIM * DIM * 2;
  short* woT = (short*)p; p += (size_t)DIM * DIM * 2;
  short* Qb  = (short*)p; p += (size_t)ROWS * DIM * 2;
  short* Kb  = (short*)p; p += (size_t)ROWS * DIM * 2;
  short* Vtb = (short*)p; p += (size_t)ROWS * DIM * 2;
  short* ctx = x1;  // x1 dead after gemm_qkv

  conv_x<<<ROWS * DIM / 4 / 256, 256, 0, stream>>>(x, x1);
  prep_weights<<<dim3(32, 32, 4), 256, 0, stream>>>(w_q, w_k, w_v, w_o,
                                                    wqT, wkT, wvT, woT);
  gemm_qkv<<<dim3(ROWS / 128, 3 * DIM / 128), 256, 0, stream>>>(
      x1, wqT, wkT, wvT, Qb, Kb, Vtb);
  attn<<<dim3(TB / 128, NB * NH), 256, 0, stream>>>(Qb, Kb, Vtb, ctx);
  gemm_out<<<dim3(ROWS / 128, DIM / 128), 256, 0, stream>>>(ctx, woT, b_o, out);
}